// Round 9
// baseline (183.463 us; speedup 1.0000x reference)
//
#include <hip/hip_runtime.h>
#include <math.h>

#define N_ROWS 4096
#define D_DIM  256
#define INV_T  (1.0f / 0.07f)

typedef _Float16 half8 __attribute__((ext_vector_type(8)));
typedef _Float16 half4 __attribute__((ext_vector_type(4)));
typedef float    f32x4 __attribute__((ext_vector_type(4)));
typedef unsigned long long u64;
typedef unsigned char u8;

#define GLOAD_LDS(gp, lp) \
    __builtin_amdgcn_global_load_lds( \
        (const __attribute__((address_space(1))) void*)(gp), \
        (__attribute__((address_space(3))) void*)(lp), 16, 0, 0)

// ---------------------------------------------------------------------------
// normalize_k (verified round-1 kernel): row-normalize -> fp16, zero accum.
// ---------------------------------------------------------------------------
__global__ __launch_bounds__(256) void normalize_k(const float* __restrict__ f,
                                                   _Float16* __restrict__ fnh,
                                                   float* __restrict__ accum) {
    const int t   = threadIdx.x;
    const int gid = blockIdx.x * 256 + t;
    if (gid < 3 * N_ROWS) accum[gid] = 0.0f;

    const int lane = t & 63;
    const int row  = blockIdx.x * 4 + (t >> 6);
    float4 v = ((const float4*)(f + (size_t)row * D_DIM))[lane];
    float s = v.x * v.x + v.y * v.y + v.z * v.z + v.w * v.w;
    #pragma unroll
    for (int off = 32; off > 0; off >>= 1) s += __shfl_xor(s, off, 64);
    float rn = 1.0f / fmaxf(sqrtf(s), 1e-8f);
    half4 h;
    h.x = (_Float16)(v.x * rn);
    h.y = (_Float16)(v.y * rn);
    h.z = (_Float16)(v.z * rn);
    h.w = (_Float16)(v.w * rn);
    *(half4*)(fnh + (size_t)row * D_DIM + lane * 4) = h;
}

// ---------------------------------------------------------------------------
// prep_k v5: mask compress as a PURE FLAT STREAMER (m13/LayerNorm pattern --
// the only pattern with measured >5 TB/s provenance on this chip).
// Round-8 post-mortem: all four previous variants (dual-stream interleave,
// serial OR-chains, row-structured wave roles) pinned at 2.3-2.75 TB/s.
// This version removes every one of those properties:
//   - 131072 wave-tasks, each = 1 KB of ONE mask (single stream per instr;
//     pm tasks are the first half, nm the second)
//   - grid-stride with COMPILE-TIME 8-iteration unroll, iterations fully
//     independent (no accumulator crossing iterations)
//   - consume: 4 compares -> nibble, one shfl_xor(1) pair-merge, even lanes
//     store 1 byte.  Bitmap layout MP/MN[row][512B], bit j <-> col j.
// Diagonal (col==row) folded in here.
// ---------------------------------------------------------------------------
__global__ __launch_bounds__(256) void prep_k(const float* __restrict__ pm,
                                              const float* __restrict__ nm,
                                              u8* __restrict__ MP,
                                              u8* __restrict__ MN) {
    const int t    = threadIdx.x;
    const int lane = t & 63;
    const int wgid = blockIdx.x * 4 + (t >> 6);   // 0..16383 (4096 blocks)

    #pragma unroll
    for (int q = 0; q < 8; ++q) {
        const int task = wgid + q * 16384;        // 0..131071
        const int mask = task >> 16;              // 0 = pm, 1 = nm
        const int m    = task & 65535;
        const int row  = m >> 4;
        const int g16  = m & 15;
        const int col0 = g16 * 256 + lane * 4;

        const float* src = (mask ? nm : pm) + (size_t)row * N_ROWS + col0;
        const float4 v = *(const float4*)src;

        unsigned bits = 0;
        bits |= (v.x != 0.f && (col0 + 0) != row) ? 1u : 0u;
        bits |= (v.y != 0.f && (col0 + 1) != row) ? 2u : 0u;
        bits |= (v.z != 0.f && (col0 + 2) != row) ? 4u : 0u;
        bits |= (v.w != 0.f && (col0 + 3) != row) ? 8u : 0u;

        const unsigned o = __shfl_xor(bits, 1, 64);
        if ((lane & 1) == 0) {
            u8* dst = mask ? MN : MP;
            dst[(size_t)row * 512 + g16 * 32 + (lane >> 1)] = (u8)(bits | (o << 4));
        }
    }
}

// ---------------------------------------------------------------------------
// fused_k v13: 128x128 tile GEMM (verified rounds 6/8: 4 waves, 4x4
// fragments of 16x16x32, 32 KB LDS, grid 32x32) + bitmap-mask epilogue.
// Mask fetch per thread per it: u64 from MP and MN at row i, byte offset
// bx*16 + wc*8 (covers cols j0+wc*64 .. +63).  Bit sh = jt*16 + grp*4 + e.
// MP/MN are 2 MB each -> L2-resident.
// ---------------------------------------------------------------------------
__global__ __launch_bounds__(256) void fused_k(const _Float16* __restrict__ fnh,
                                               const u8* __restrict__ MP,
                                               const u8* __restrict__ MN,
                                               float* __restrict__ accum) {
    __shared__ __align__(16) _Float16 lds[2 * 128 * 64];   // 32 KB
    _Float16* As = lds;               // [128][64]
    _Float16* Bs = lds + 128 * 64;    // [128][64]

    const int t    = threadIdx.x;
    const int lane = t & 63;
    const int w    = t >> 6;        // wave 0..3
    const int wr   = w >> 1;        // i-half (64 rows)
    const int wc   = w & 1;         // j-half (64 cols)
    const int bx   = blockIdx.x;
    const int i0   = blockIdx.y * 128;
    const int j0   = bx * 128;
    const int l15  = lane & 15;
    const int grp  = lane >> 4;

    const int srow  = t >> 3;                          // 0..31
    const int sslot = ((t & 7) ^ ((t >> 3) & 7)) * 8;  // swizzled granule

    f32x4 acc[4][4];  // [jt][it]
    #pragma unroll
    for (int a = 0; a < 4; ++a)
        #pragma unroll
        for (int b = 0; b < 4; ++b)
            acc[a][b] = (f32x4){0.f, 0.f, 0.f, 0.f};

    for (int k0 = 0; k0 < D_DIM; k0 += 64) {
        #pragma unroll
        for (int q = 0; q < 4; ++q) {
            GLOAD_LDS(fnh + (size_t)(i0 + q * 32 + srow) * D_DIM + k0 + sslot,
                      &As[q * 2048 + w * 512]);
            GLOAD_LDS(fnh + (size_t)(j0 + q * 32 + srow) * D_DIM + k0 + sslot,
                      &Bs[q * 2048 + w * 512]);
        }
        __syncthreads();

        #pragma unroll
        for (int kk = 0; kk < 2; ++kk) {
            half8 aj[4], bi[4];
            #pragma unroll
            for (int jt = 0; jt < 4; ++jt) {
                const int r = wc * 64 + jt * 16 + l15;
                aj[jt] = *(const half8*)&Bs[r * 64 + (((kk * 4 + grp) ^ (r & 7)) << 3)];
            }
            #pragma unroll
            for (int it = 0; it < 4; ++it) {
                const int r = wr * 64 + it * 16 + l15;
                bi[it] = *(const half8*)&As[r * 64 + (((kk * 4 + grp) ^ (r & 7)) << 3)];
            }
            #pragma unroll
            for (int jt = 0; jt < 4; ++jt)
                #pragma unroll
                for (int it = 0; it < 4; ++it)
                    acc[jt][it] = __builtin_amdgcn_mfma_f32_16x16x32_f16(
                        aj[jt], bi[it], acc[jt][it], 0, 0, 0);
        }
        __syncthreads();
    }

    // ---- epilogue: 2 u64 bitmap loads per it, exp/fma, reduce over grp ----
    const int mrow0 = i0 + wr * 64 + l15;
    const size_t moff = (size_t)bx * 16 + wc * 8;   // byte offset into a row

    #pragma unroll
    for (int it = 0; it < 4; ++it) {
        const int i = mrow0 + it * 16;
        const u64 wpv = *(const u64*)(MP + (size_t)i * 512 + moff);
        const u64 wnv = *(const u64*)(MN + (size_t)i * 512 + moff);
        float negp = 0.f, posp = 0.f, np = 0.f;
        #pragma unroll
        for (int jt = 0; jt < 4; ++jt) {
            #pragma unroll
            for (int e = 0; e < 4; ++e) {
                const int sh = jt * 16 + grp * 4 + e;
                const float cs = acc[jt][it][e] * INV_T;
                const float pf = (float)((wpv >> sh) & 1ull);
                const float nf = (float)((wnv >> sh) & 1ull);
                negp = fmaf(__expf(cs), nf, negp);
                posp = fmaf(cs, pf, posp);
                np  += pf;
            }
        }
        negp += __shfl_xor(negp, 16, 64);
        posp += __shfl_xor(posp, 16, 64);
        np   += __shfl_xor(np,   16, 64);
        negp += __shfl_xor(negp, 32, 64);
        posp += __shfl_xor(posp, 32, 64);
        np   += __shfl_xor(np,   32, 64);
        if (grp == 0) {
            atomicAdd(&accum[i], negp);
            atomicAdd(&accum[N_ROWS + i], posp);
            atomicAdd(&accum[2 * N_ROWS + i], np);
        }
    }
}

// ---------------------------------------------------------------------------
// final_k: reduction over rows -> scalar loss
// ---------------------------------------------------------------------------
__global__ __launch_bounds__(256) void final_k(const float* __restrict__ accum,
                                               float* __restrict__ out) {
    const int t = threadIdx.x;
    float s = 0.f;
    for (int i = t; i < N_ROWS; i += 256) {
        float neg  = accum[i];
        float posc = accum[N_ROWS + i];
        float np   = accum[2 * N_ROWS + i];
        float term = (np > 0.f) ? (posc - np * logf(fmaxf(neg, 1e-30f))) / np : 0.f;
        s += term;
    }
    #pragma unroll
    for (int off = 32; off > 0; off >>= 1) s += __shfl_xor(s, off, 64);
    __shared__ float wsum[4];
    if ((t & 63) == 0) wsum[t >> 6] = s;
    __syncthreads();
    if (t == 0) {
        float tot = wsum[0] + wsum[1] + wsum[2] + wsum[3];
        out[0] = -tot / (float)N_ROWS;
    }
}

// ---------------------------------------------------------------------------
// ws layout: fnh 2 MB | accum 64 KB | MP 2 MB | MN 2 MB  (~6.1 MB total)
// ---------------------------------------------------------------------------
extern "C" void kernel_launch(void* const* d_in, const int* in_sizes, int n_in,
                              void* d_out, int out_size, void* d_ws, size_t ws_size,
                              hipStream_t stream) {
    const float* feat = (const float*)d_in[0];
    const float* pm   = (const float*)d_in[1];
    const float* nm   = (const float*)d_in[2];
    float* out = (float*)d_out;

    const size_t FNH_B = (size_t)N_ROWS * D_DIM * sizeof(_Float16);  // 2 MB
    const size_t ACC_B = 65536;
    const size_t MAP_B = (size_t)N_ROWS * 512;                       // 2 MB

    _Float16* fnh = (_Float16*)d_ws;
    float* accum  = (float*)((char*)d_ws + FNH_B);
    u8* MP        = (u8*)((char*)d_ws + FNH_B + ACC_B);
    u8* MN        = (u8*)((char*)d_ws + FNH_B + ACC_B + MAP_B);

    normalize_k<<<N_ROWS / 4, 256, 0, stream>>>(feat, fnh, accum);
    prep_k<<<4096, 256, 0, stream>>>(pm, nm, MP, MN);

    dim3 grid(N_ROWS / 128, N_ROWS / 128);
    fused_k<<<grid, 256, 0, stream>>>(fnh, MP, MN, accum);

    final_k<<<1, 256, 0, stream>>>(accum, out);
}